// Round 1
// baseline (473.224 us; speedup 1.0000x reference)
//
#include <hip/hip_runtime.h>
#include <cmath>

namespace {
constexpr int BN = 1024;
constexpr int NC = 96;
constexpr int MT = 256;
constexpr int UL = 40;
constexpr int LS = 81;   // 2*UL+1 states
constexpr int LSP = 82;  // padded row stride (even -> 8B-aligned float2 stores)

__device__ __forceinline__ float wave_sum1(float a) {
#pragma unroll
  for (int off = 32; off >= 1; off >>= 1) a += __shfl_xor(a, off, 64);
  return a;
}

__device__ __forceinline__ void wave_sum2(float& a, float& b) {
#pragma unroll
  for (int off = 32; off >= 1; off >>= 1) {
    a += __shfl_xor(a, off, 64);
    b += __shfl_xor(b, off, 64);
  }
}

// One wave (64 lanes) per batch item. Lane i owns states s=2i and s=2i+1.
__global__ __launch_bounds__(64) void ctc_kernel(
    const float* __restrict__ gout, const int* __restrict__ glabel,
    const int* __restrict__ gw, float* __restrict__ braw,
    float* __restrict__ loss_out) {
  const int b = blockIdx.x;
  const int i = threadIdx.x;
  const float* P = gout + (size_t)b * (NC * MT);  // P[c*MT + t]
  const int* lab = glabel + b * UL;
  const int T = gw[b] >> 2;  // w // 4, w in [512,1024] -> T in [128,256]

  const int s0 = 2 * i, s1 = 2 * i + 1;
  const bool has0 = (s0 < LS);  // i <= 40
  const bool has1 = (s1 < LS);  // i <= 39

  const int labi  = (i < UL) ? lab[i] : 0;
  const int labm  = (i >= 1 && i < UL) ? lab[i - 1] : 0;
  const int rlabi = (i < UL) ? lab[UL - 1 - i] : 0;   // reversed labels
  const int rlabm = (i >= 1 && i < UL) ? lab[UL - i] : 0;

  float* brow0 = braw + (size_t)b * (MT * LSP);

  // -------- Phase 1: beta_raw = alpha on class-flipped probs + reversed
  // labels; each row stored to workspace --------
  {
    const float* pB = P + (size_t)(NC - 1) * MT;          // flipped blank = 95
    const float* p1 = P + (size_t)(NC - 1 - rlabi) * MT;  // flipped label
    const bool skip1 = has1 && (i >= 1) && (rlabi != rlabm);

    float v0, v1;
    {  // t = 0 row
      float a0 = (i == 0) ? pB[0] : 0.f;
      float a1 = (i == 0) ? p1[0] : 0.f;
      float c = wave_sum1(a0 + a1);
      if (c > 0.f) { a0 /= c; a1 /= c; }
      v0 = a0; v1 = a1;
      if (has1) *reinterpret_cast<float2*>(brow0 + s0) = make_float2(v0, v1);
      else if (has0) brow0[s0] = v0;
    }
    float pb_c = pB[(1 < T) ? 1 : 0];
    float pl_c = p1[(1 < T) ? 1 : 0];
    for (int t = 1; t < T; ++t) {
      const int tn = (t + 1 < T) ? (t + 1) : t;  // prefetch next step's probs
      const float pb_n = pB[tn];
      const float pl_n = p1[tn];
      float pm1 = __shfl_up(v1, 1, 64);  // prev[2i-1]
      if (i == 0) pm1 = 0.f;
      const int start = LS - 2 * (T - t);  // may be negative
      float n0 = 0.f, n1 = 0.f;
      if (has0) {
        n0 = (v0 + ((i > 0) ? pm1 : 0.f)) * pb_c;
        if (s0 < start) n0 = 0.f;
      }
      if (has1) {
        n1 = (v1 + v0 + (skip1 ? pm1 : 0.f)) * pl_c;
        if (s1 < start) n1 = 0.f;
      }
      float c = wave_sum1(n0 + n1);
      if (c > 0.f) { n0 /= c; n1 /= c; }
      v0 = n0; v1 = n1;
      float* row = brow0 + (size_t)t * LSP;
      if (has1) *reinterpret_cast<float2*>(row + s0) = make_float2(v0, v1);
      else if (has0) row[s0] = v0;
      pb_c = pb_n; pl_c = pl_n;
    }
  }

  // -------- Phase 2: alpha + likelihood combine --------
  {
    const float* pB = P;                        // blank = class 0
    const float* p1 = P + (size_t)labi * MT;    // label class
    const bool skip1 = has1 && (i >= 1) && (labi != labm);

    double loss = 0.0;
    float v0, v1;
    {  // t = 0
      float a0 = (i == 0) ? pB[0] : 0.f;
      float a1 = (i == 0) ? p1[0] : 0.f;
      float c = wave_sum1(a0 + a1);
      if (c > 0.f) { a0 /= c; a1 /= c; }
      v0 = a0; v1 = a1;
      const float* br = brow0 + (size_t)(T - 1) * LSP;
      float r = 0.f;
      if (has0) r += v0 * br[LS - 1 - s0] / pB[0];
      if (has1) r += v1 * br[LS - 1 - s1] / p1[0];
      float lh = wave_sum1(r);
      loss -= (double)logf(lh);
    }
    float pb_c = pB[(1 < T) ? 1 : 0];
    float pl_c = p1[(1 < T) ? 1 : 0];
    for (int t = 1; t < T; ++t) {
      const int tn = (t + 1 < T) ? (t + 1) : t;
      const float pb_n = pB[tn];
      const float pl_n = p1[tn];
      float pm1 = __shfl_up(v1, 1, 64);
      if (i == 0) pm1 = 0.f;
      const int start = LS - 2 * (T - t);
      float n0 = 0.f, n1 = 0.f;
      if (has0) {
        n0 = (v0 + ((i > 0) ? pm1 : 0.f)) * pb_c;
        if (s0 < start) n0 = 0.f;
      }
      if (has1) {
        n1 = (v1 + v0 + (skip1 ? pm1 : 0.f)) * pl_c;
        if (s1 < start) n1 = 0.f;
      }
      // fused reductions: c (renorm) and lh (b-weighted, pre-normalized)
      const float* br = brow0 + (size_t)(T - 1 - t) * LSP;
      float r0 = 0.f, r1 = 0.f;
      if (has0) r0 = n0 * br[LS - 1 - s0] / pb_c;
      if (has1) r1 = n1 * br[LS - 1 - s1] / pl_c;
      float cs = n0 + n1, rs = r0 + r1;
      wave_sum2(cs, rs);
      float lh;
      if (cs > 0.f) { n0 /= cs; n1 /= cs; lh = rs / cs; }
      else lh = rs;
      v0 = n0; v1 = n1;
      loss -= (double)logf(lh);
      pb_c = pb_n; pl_c = pl_n;
    }
    if (i == 0) loss_out[b] = (float)loss;
  }
}

__global__ void reduce_kernel(const float* __restrict__ loss_in,
                              float* __restrict__ out) {
  __shared__ double sm[256];
  const int tid = threadIdx.x;
  double s = 0.0;
  for (int k = tid; k < BN; k += 256) s += (double)loss_in[k];
  sm[tid] = s;
  __syncthreads();
  for (int w = 128; w >= 1; w >>= 1) {
    if (tid < w) sm[tid] += sm[tid + w];
    __syncthreads();
  }
  if (tid == 0) out[0] = (float)sm[0];
}
}  // namespace

extern "C" void kernel_launch(void* const* d_in, const int* in_sizes, int n_in,
                              void* d_out, int out_size, void* d_ws, size_t ws_size,
                              hipStream_t stream) {
  const float* gout = (const float*)d_in[0];
  const int* glabel = (const int*)d_in[1];
  const int* gw = (const int*)d_in[2];
  float* braw = (float*)d_ws;                       // BN*MT*LSP floats (~82 MB)
  float* loss = braw + (size_t)BN * MT * LSP;       // BN floats
  ctc_kernel<<<BN, 64, 0, stream>>>(gout, glabel, gw, braw, loss);
  reduce_kernel<<<1, 256, 0, stream>>>(loss, (float*)d_out);
}

// Round 3
// 347.334 us; speedup vs baseline: 1.3624x; 1.3624x over previous
//
#include <hip/hip_runtime.h>
#include <cmath>

namespace {
constexpr int BN = 1024;
constexpr int NC = 96;
constexpr int MT = 256;
constexpr int UL = 40;
constexpr int LS = 81;   // 2*UL+1 states
constexpr int LSP = 82;  // padded row stride

// DPP helpers: cross-lane on the VALU pipe (~8 cyc/stage) instead of
// ds_swizzle (~120 cyc/stage). bound_ctrl=true -> out-of-range lanes read 0.
// dpp_ctrl must be a compile-time constant -> template parameter.
template <int CTRL>
__device__ __forceinline__ float dppf(float v) {
  return __builtin_bit_cast(
      float, __builtin_amdgcn_update_dpp(0, __builtin_bit_cast(int, v), CTRL,
                                         0xf, 0xf, true));
}
// Full 64-lane sum; result uniform (readlane -> SGPR broadcast).
__device__ __forceinline__ float wave_sum(float x) {
  x += dppf<0x111>(x);  // row_shr:1
  x += dppf<0x112>(x);  // row_shr:2
  x += dppf<0x114>(x);  // row_shr:4
  x += dppf<0x118>(x);  // row_shr:8  -> lane15 of each row has row sum
  x += dppf<0x142>(x);  // row_bcast:15
  x += dppf<0x143>(x);  // row_bcast:31 -> lane 63 has full sum
  return __builtin_bit_cast(
      float, __builtin_amdgcn_readlane(__builtin_bit_cast(int, x), 63));
}
// lane i <- lane i-1 (lane 0 <- 0): wave_shr:1
__device__ __forceinline__ float wave_shr1(float v) { return dppf<0x138>(v); }

// One wave (64 lanes) per batch item. Lane i owns states s=2i, 2i+1.
__global__ __launch_bounds__(64) void ctc_kernel(
    const float* __restrict__ gout, const int* __restrict__ glabel,
    const int* __restrict__ gw, float* __restrict__ braw,
    float* __restrict__ loss_out) {
  const int b = blockIdx.x;
  const int i = threadIdx.x;
  const float* P = gout + (size_t)b * (NC * MT);  // P[c*MT + t]
  const int* lab = glabel + b * UL;
  const int T = gw[b] >> 2;  // T in [128,256]

  const int s0 = 2 * i, s1 = s0 + 1;
  const bool has0 = (s0 < LS);
  const bool has1 = (s1 < LS);

  const int labi = (i < UL) ? lab[i] : 0;
  const int labm = (i >= 1 && i < UL) ? lab[i - 1] : 0;
  const int rlabi = (i < UL) ? lab[UL - 1 - i] : 0;
  const int rlabm = (i >= 1 && i < UL) ? lab[UL - i] : 0;

  float* brow0 = braw + (size_t)b * (MT * LSP);

  // ---------- Phase 1: beta_raw rows -> workspace ----------
  {
    const float* pB = P + (size_t)(NC - 1) * MT;
    const float* pL = P + (size_t)(NC - 1 - rlabi) * MT;  // per-lane row
    const bool skip1 = has1 && (i >= 1) && (rlabi != rlabm);

    float v0, v1;
    {  // t = 0
      float a0 = (i == 0) ? pB[0] : 0.f;
      float a1 = (i == 0) ? pL[0] : 0.f;
      float c = wave_sum(a0 + a1);
      if (c > 0.f) {
        float inv = 1.f / c;
        a0 *= inv; a1 *= inv;
      }
      v0 = a0; v1 = a1;
      if (has1) *reinterpret_cast<float2*>(brow0 + s0) = make_float2(v0, v1);
      else if (has0) brow0[s0] = v0;
    }
    // depth-3 register pipeline on prob reads (keeps vmcnt off the chain)
    float pb_c = pB[1], pl_c = pL[1];
    float pb_1 = pB[2], pl_1 = pL[2];
    float pb_2 = pB[3], pl_2 = pL[3];
    for (int t = 1; t < T; ++t) {
      float pm1 = wave_shr1(v1);  // prev[2i-1]; lane0 -> 0
      const int start = LS - 2 * (T - t);
      float n0 = 0.f, n1 = 0.f;
      if (has0) {
        n0 = (v0 + pm1) * pb_c;
        if (s0 < start) n0 = 0.f;
      }
      if (has1) {
        n1 = (v1 + v0 + (skip1 ? pm1 : 0.f)) * pl_c;
        if (s1 < start) n1 = 0.f;
      }
      float cs = wave_sum(n0 + n1);
      if (cs > 0.f) {
        float inv = 1.f / cs;
        n0 *= inv; n1 *= inv;
      }
      v0 = n0; v1 = n1;
      float* row = brow0 + (size_t)t * LSP;
      if (has1) *reinterpret_cast<float2*>(row + s0) = make_float2(v0, v1);
      else if (has0) row[s0] = v0;
      const int tn = (t + 3 <= T - 1) ? t + 3 : T - 1;
      pb_c = pb_1; pb_1 = pb_2; pb_2 = pB[tn];
      pl_c = pl_1; pl_1 = pl_2; pl_2 = pL[tn];
    }
  }

  __threadfence_block();  // drain braw writes (same-wave RAW via cache)
  __syncthreads();

  // ---------- Phase 2: alpha + fused likelihood ----------
  {
    const float* pB = P;                      // blank = class 0
    const float* pL = P + (size_t)labi * MT;  // per-lane label row
    const bool skip1 = has1 && (i >= 1) && (labi != labm);
    const int r0i = LS - 1 - s0;  // 80-2i (valid only if has0)

    double loss = 0.0;
    float v0, v1;
    {  // t = 0
      float a0 = (i == 0) ? pB[0] : 0.f;
      float a1 = (i == 0) ? pL[0] : 0.f;
      float c = wave_sum(a0 + a1);
      if (c > 0.f) {
        float inv = 1.f / c;
        a0 *= inv; a1 *= inv;
      }
      v0 = a0; v1 = a1;
      const float* br = brow0 + (size_t)(T - 1) * LSP;
      float r = 0.f;
      if (has0) r += v0 * br[r0i] / pB[0];
      if (has1) r += v1 * br[r0i - 1] / pL[0];
      float lh = wave_sum(r);
      loss -= (double)__logf(lh);
    }
    // prob pipeline depth-3
    float pb_c = pB[1], pl_c = pL[1];
    float pb_1 = pB[2], pl_1 = pL[2];
    float pb_2 = pB[3], pl_2 = pL[3];
    // beta-row pipeline depth-3 (step t uses row T-1-t)
    float bc0, bc1, b10, b11, b20, b21;
    {
      const float* r1p = brow0 + (size_t)(T - 2) * LSP;
      const float* r2p = brow0 + (size_t)(T - 3) * LSP;
      const float* r3p = brow0 + (size_t)(T - 4) * LSP;
      bc0 = has0 ? r1p[r0i] : 0.f;
      bc1 = has1 ? r1p[r0i - 1] : 0.f;
      b10 = has0 ? r2p[r0i] : 0.f;
      b11 = has1 ? r2p[r0i - 1] : 0.f;
      b20 = has0 ? r3p[r0i] : 0.f;
      b21 = has1 ? r3p[r0i - 1] : 0.f;
    }
    for (int t = 1; t < T; ++t) {
      float pm1 = wave_shr1(v1);
      const int start = LS - 2 * (T - t);
      float n0 = 0.f, n1 = 0.f;
      if (has0) {
        n0 = (v0 + pm1) * pb_c;
        if (s0 < start) n0 = 0.f;
      }
      if (has1) {
        n1 = (v1 + v0 + (skip1 ? pm1 : 0.f)) * pl_c;
        if (s1 < start) n1 = 0.f;
      }
      float cs = wave_sum(n0 + n1);  // recurrence chain
      // loss side-chain (pre-normalized; lh = rs/cs)
      float r0 = has0 ? n0 * bc0 / pb_c : 0.f;
      float r1 = has1 ? n1 * bc1 / pl_c : 0.f;
      float rs = wave_sum(r0 + r1);
      float inv = (cs > 0.f) ? 1.f / cs : 1.f;
      v0 = n0 * inv; v1 = n1 * inv;
      float lh = (cs > 0.f) ? rs / cs : rs;
      loss -= (double)__logf(lh);
      // rotate pipelines (fill for step t+3)
      const int tn = (t + 3 <= T - 1) ? t + 3 : T - 1;
      pb_c = pb_1; pb_1 = pb_2; pb_2 = pB[tn];
      pl_c = pl_1; pl_1 = pl_2; pl_2 = pL[tn];
      bc0 = b10; bc1 = b11; b10 = b20; b11 = b21;
      const float* brp = brow0 + (size_t)(T - 1 - tn) * LSP;
      b20 = has0 ? brp[r0i] : 0.f;
      b21 = has1 ? brp[r0i - 1] : 0.f;
    }
    if (i == 0) loss_out[b] = (float)loss;
  }
}

__global__ void reduce_kernel(const float* __restrict__ loss_in,
                              float* __restrict__ out) {
  __shared__ double sm[256];
  const int tid = threadIdx.x;
  double s = 0.0;
  for (int k = tid; k < BN; k += 256) s += (double)loss_in[k];
  sm[tid] = s;
  __syncthreads();
  for (int w = 128; w >= 1; w >>= 1) {
    if (tid < w) sm[tid] += sm[tid + w];
    __syncthreads();
  }
  if (tid == 0) out[0] = (float)sm[0];
}
}  // namespace

extern "C" void kernel_launch(void* const* d_in, const int* in_sizes, int n_in,
                              void* d_out, int out_size, void* d_ws, size_t ws_size,
                              hipStream_t stream) {
  const float* gout = (const float*)d_in[0];
  const int* glabel = (const int*)d_in[1];
  const int* gw = (const int*)d_in[2];
  float* braw = (float*)d_ws;                  // BN*MT*LSP floats (~86 MB)
  float* loss = braw + (size_t)BN * MT * LSP;  // BN floats
  ctc_kernel<<<BN, 64, 0, stream>>>(gout, glabel, gw, braw, loss);
  reduce_kernel<<<1, 256, 0, stream>>>(loss, (float*)d_out);
}

// Round 6
// 322.819 us; speedup vs baseline: 1.4659x; 1.0759x over previous
//
#include <hip/hip_runtime.h>
#include <cmath>

namespace {
constexpr int BN = 1024;
constexpr int NC = 96;
constexpr int MT = 256;
constexpr int UL = 40;
constexpr int LS = 81;   // 2*UL+1 states
constexpr int LSP = 82;  // padded row stride (floats)

template <int CTRL>
__device__ __forceinline__ float dppf(float v) {
  return __builtin_bit_cast(
      float, __builtin_amdgcn_update_dpp(0, __builtin_bit_cast(int, v), CTRL,
                                         0xf, 0xf, true));
}
__device__ __forceinline__ float rl63(float x) {
  return __builtin_bit_cast(
      float, __builtin_amdgcn_readlane(__builtin_bit_cast(int, x), 63));
}
__device__ __forceinline__ float wave_sum(float x) {
  x += dppf<0x111>(x);
  x += dppf<0x112>(x);
  x += dppf<0x114>(x);
  x += dppf<0x118>(x);
  x += dppf<0x142>(x);
  x += dppf<0x143>(x);
  return rl63(x);
}
__device__ __forceinline__ void wave_sum2(float& a, float& b) {
  a += dppf<0x111>(a); b += dppf<0x111>(b);
  a += dppf<0x112>(a); b += dppf<0x112>(b);
  a += dppf<0x114>(a); b += dppf<0x114>(b);
  a += dppf<0x118>(a); b += dppf<0x118>(b);
  a += dppf<0x142>(a); b += dppf<0x142>(b);
  a += dppf<0x143>(a); b += dppf<0x143>(b);
  a = rl63(a); b = rl63(b);
}
// lane i <- lane i-1 (lane 0 <- 0)
__device__ __forceinline__ float wave_shr1(float v) { return dppf<0x138>(v); }
__device__ __forceinline__ float fast_rcp(float x) {
  return __builtin_amdgcn_rcpf(x);
}

constexpr float FQ = 1e8f;     // nominal row scale (headroom vs mask shocks)
constexpr float SEPS = 1e-30f; // ss floor inside rcp (NaN-proof)

// One wave per batch item. Lane i owns states s=2i, 2i+1.
// Chains run UNNORMALIZED; scale controlled off-chain by deadbeat compensated
// rescale r_t = F/(S_{t-3}*r_{t-1}*r_{t-2})  =>  row sum ss_t = F*c_{t-2}c_{t-1}c_t
// exactly (FIR, shock-immune). Normalization recovered from stored row sums.
__global__ __launch_bounds__(64) void ctc_kernel(
    const float* __restrict__ gout, const int* __restrict__ glabel,
    const int* __restrict__ gw, float* __restrict__ braw,
    float* __restrict__ sums_g, float* __restrict__ loss_out) {
  const int b = blockIdx.x;
  const int i = threadIdx.x;
  const float* P = gout + (size_t)b * (NC * MT);  // P[c*MT + t]
  const int* lab = glabel + b * UL;
  const int T = gw[b] >> 2;  // [128,256]

  const int s0 = 2 * i, s1 = s0 + 1;
  const float h0f = (i <= 40) ? 1.f : 0.f;
  const float h1f = (i <= 39) ? 1.f : 0.f;

  const int labi = (i < UL) ? lab[i] : 0;
  const int labm = (i >= 1 && i < UL) ? lab[i - 1] : 0;
  const int rlabi = (i < UL) ? lab[UL - 1 - i] : 0;
  const int rlabm = (i >= 1 && i < UL) ? lab[UL - i] : 0;

  float* brow0 = braw + (size_t)b * (MT * LSP);
  float* sums = sums_g + (size_t)b * MT;
  const int iw = (i <= 40) ? i : 40;

  // ---- Phase 1: beta chain (flipped probs, reversed labels). Rows stored
  // REVERSED (rev[j] = raw[80-j] == reference b[t][j] for row T-1-t), delayed
  // one step so shr1(v1) doubles as recurrence input and store operand.
  {
    const float* pB = P + (size_t)(NC - 1) * MT;
    const float* pL = P + (size_t)(NC - 1 - rlabi) * MT;
    const float mskf = (i >= 1 && i <= 39 && rlabi != rlabm) ? 1.f : 0.f;

    float v0 = (i == 0) ? pB[0] : 0.f;
    float v1 = (i == 0) ? pL[0] : 0.f;
    float ss = wave_sum(v0 + v1);
    if (i == 0) sums[0] = ss;
    float r0q = FQ * fast_rcp(fmaxf(ss, SEPS));
    float r1q = FQ * fast_rcp(fmaxf(ss * r0q, SEPS));
    float r2q = FQ * fast_rcp(fmaxf(ss * r0q * r1q, SEPS));

    float pbq0 = pB[1], pbq1 = pB[2], pbq2 = pB[3];
    float plq0 = pL[1], plq1 = pL[2], plq2 = pL[3];
    float2* wp = (float2*)(brow0 + (80 - 2 * iw));  // row t-1 written at t
    for (int t = 1; t < T; ++t) {
      float pm1 = wave_shr1(v1);  // row t-1 state 2i-1
      if (i <= 40) *wp = make_float2(v0, pm1);
      wp += (LSP / 2);
      const float rh0 = r0q * h0f, rh1 = r0q * h1f;
      const float prb = pbq0 * rh0, prl = plq0 * rh1;
      float u0 = v0 + pm1;
      float u1 = (v0 + v1) + pm1 * mskf;
      const int start = LS - 2 * (T - t);
      if (s0 < start) u0 = 0.f;
      if (s1 < start) u1 = 0.f;
      float n0 = u0 * prb;
      float n1 = u1 * prl;
      float ssn = wave_sum(n0 + n1);
      if (i == 0) sums[t] = ssn;
      // deadbeat rescale, clamped (NaN/inf-proof)
      float rn = FQ * fast_rcp(fmaxf(ssn, SEPS) * r1q * r2q);
      r0q = r1q; r1q = r2q; r2q = rn;
      int tn = t + 3; if (tn > T - 1) tn = T - 1;
      pbq0 = pbq1; pbq1 = pbq2; pbq2 = pB[tn];
      plq0 = plq1; plq1 = plq2; plq2 = pL[tn];
      v0 = n0; v1 = n1;
    }
    float pm1f = wave_shr1(v1);  // final row T-1
    if (i <= 40) *wp = make_float2(v0, pm1f);
  }

  __threadfence_block();
  __syncthreads();

  // ---- Phase 2: alpha chain + fused likelihood.
  // lh_t = ds/(ss*sq): a/p = u*r/ss exactly (any r); b_norm = b~/sq.
  {
    const float* pB = P;
    const float* pL = P + (size_t)labi * MT;
    const float mskf = (i >= 1 && i <= 39 && labi != labm) ? 1.f : 0.f;
    const float* bbase = brow0 + 2 * iw;  // lane's float2 slot (b[t][2i])

    float loss = 0.f;
    float v0 = (i == 0) ? pB[0] : 0.f;
    float v1 = (i == 0) ? pL[0] : 0.f;
    float2 bT = *(const float2*)(bbase + (size_t)(T - 1) * LSP);
    float ss0 = v0 + v1;
    float ds0 = (i == 0) ? (bT.x + bT.y) : 0.f;
    wave_sum2(ss0, ds0);
    {
      float lh = ds0 * fast_rcp(fmaxf(ss0, SEPS)) *
                 fast_rcp(fmaxf(sums[T - 1], SEPS));
      loss -= __logf(fmaxf(lh, 1e-37f));
    }
    float r0q = FQ * fast_rcp(fmaxf(ss0, SEPS));
    float r1q = FQ * fast_rcp(fmaxf(ss0 * r0q, SEPS));
    float r2q = FQ * fast_rcp(fmaxf(ss0 * r0q * r1q, SEPS));

    float pbq0 = pB[1], pbq1 = pB[2], pbq2 = pB[3];
    float plq0 = pL[1], plq1 = pL[2], plq2 = pL[3];
    float2 bq0 = *(const float2*)(bbase + (size_t)(T - 2) * LSP);
    float2 bq1 = *(const float2*)(bbase + (size_t)(T - 3) * LSP);
    float2 bq2 = *(const float2*)(bbase + (size_t)(T - 4) * LSP);
    float2 bq3 = *(const float2*)(bbase + (size_t)(T - 5) * LSP);
    float sq0 = sums[T - 2], sq1 = sums[T - 3], sq2 = sums[T - 4],
          sq3 = sums[T - 5];
    for (int t = 1; t < T; ++t) {
      float pm1 = wave_shr1(v1);
      const float rh0 = r0q * h0f, rh1 = r0q * h1f;
      const float prb = pbq0 * rh0, prl = plq0 * rh1;
      float u0 = v0 + pm1;
      float u1 = (v0 + v1) + pm1 * mskf;
      const int start = LS - 2 * (T - t);
      if (s0 < start) u0 = 0.f;
      if (s1 < start) u1 = 0.f;
      float n0 = u0 * prb;
      float n1 = u1 * prl;
      float ss = n0 + n1;
      // overflow-safe order: (u*r) is deadbeat-bounded ~96F; r alone is not.
      float t0 = u0 * rh0, t1 = u1 * rh1;
      float ds = fmaf(t1, bq0.y, t0 * bq0.x);
      wave_sum2(ss, ds);
      {
        float lh = ds * fast_rcp(fmaxf(ss, SEPS)) *
                   fast_rcp(fmaxf(sq0, SEPS));
        loss -= __logf(fmaxf(lh, 1e-37f));
      }
      float rn = FQ * fast_rcp(fmaxf(ss, SEPS) * r1q * r2q);
      r0q = r1q; r1q = r2q; r2q = rn;
      int tn = t + 3; if (tn > T - 1) tn = T - 1;
      pbq0 = pbq1; pbq1 = pbq2; pbq2 = pB[tn];
      plq0 = plq1; plq1 = plq2; plq2 = pL[tn];
      int bi = T - 5 - t; if (bi < 0) bi = 0;
      bq0 = bq1; bq1 = bq2; bq2 = bq3;
      bq3 = *(const float2*)(bbase + (size_t)bi * LSP);
      sq0 = sq1; sq1 = sq2; sq2 = sq3;
      sq3 = sums[bi];
      v0 = n0; v1 = n1;
    }
    if (i == 0) {
      // finite no matter what (fmaxf/fminf absorb NaN per IEEE semantics)
      loss_out[b] = fminf(fmaxf(loss, -1e30f), 1e30f);
    }
  }
}

__global__ void reduce_kernel(const float* __restrict__ loss_in,
                              float* __restrict__ out) {
  __shared__ double sm[256];
  const int tid = threadIdx.x;
  double s = 0.0;
  for (int k = tid; k < BN; k += 256) s += (double)loss_in[k];
  sm[tid] = s;
  __syncthreads();
  for (int w = 128; w >= 1; w >>= 1) {
    if (tid < w) sm[tid] += sm[tid + w];
    __syncthreads();
  }
  if (tid == 0) out[0] = (float)sm[0];
}
}  // namespace

extern "C" void kernel_launch(void* const* d_in, const int* in_sizes, int n_in,
                              void* d_out, int out_size, void* d_ws, size_t ws_size,
                              hipStream_t stream) {
  const float* gout = (const float*)d_in[0];
  const int* glabel = (const int*)d_in[1];
  const int* gw = (const int*)d_in[2];
  float* braw = (float*)d_ws;                  // BN*MT*LSP floats (~86 MB)
  float* sums = braw + (size_t)BN * MT * LSP;  // BN*MT floats (~1 MB)
  float* loss = sums + (size_t)BN * MT;        // BN floats
  ctc_kernel<<<BN, 64, 0, stream>>>(gout, glabel, gw, braw, sums, loss);
  reduce_kernel<<<1, 256, 0, stream>>>(loss, (float*)d_out);
}

// Round 7
// 247.677 us; speedup vs baseline: 1.9106x; 1.3034x over previous
//
#include <hip/hip_runtime.h>
#include <cmath>

namespace {
constexpr int BN = 1024;
constexpr int NC = 96;
constexpr int MT = 256;
constexpr int UL = 40;
constexpr int LS = 81;    // 2*UL+1 states
constexpr int PAIRS = 41; // pairs per row (lane i -> states 2i, 2i+1)

template <int CTRL>
__device__ __forceinline__ float dppf(float v) {
  return __builtin_bit_cast(
      float, __builtin_amdgcn_update_dpp(0, __builtin_bit_cast(int, v), CTRL,
                                         0xf, 0xf, true));
}
__device__ __forceinline__ float rl63(float x) {
  return __builtin_bit_cast(
      float, __builtin_amdgcn_readlane(__builtin_bit_cast(int, x), 63));
}
__device__ __forceinline__ float wave_sum(float x) {
  x += dppf<0x111>(x);
  x += dppf<0x112>(x);
  x += dppf<0x114>(x);
  x += dppf<0x118>(x);
  x += dppf<0x142>(x);
  x += dppf<0x143>(x);
  return rl63(x);
}
// lane i <- lane i-1 (lane 0 <- 0)
__device__ __forceinline__ float wave_shr1(float v) { return dppf<0x138>(v); }
__device__ __forceinline__ float fast_rcp(float x) {
  return __builtin_amdgcn_rcpf(x);
}
__device__ __forceinline__ unsigned short f2bf(float x) {
  return (unsigned short)(__builtin_bit_cast(unsigned, x) >> 16);  // truncate
}
__device__ __forceinline__ float bf2f(unsigned short h) {
  return __builtin_bit_cast(float, (unsigned)h << 16);
}
__device__ __forceinline__ ushort2 pack2(float a, float b) {
  ushort2 r; r.x = f2bf(a); r.y = f2bf(b); return r;
}

constexpr float FQ = 1e8f;      // nominal row scale (shock headroom)
constexpr float SEPS = 1e-30f;  // rcp-input floor (NaN-proof)

// One wave per (item, phase). Lane i owns states s=2i, 2i+1. Chains run
// UNNORMALIZED with deadbeat compensated rescale r_t = F/(S_{t-3} r_{t-1}
// r_{t-2}) (row scale = product of last three step multipliers exactly; FIR,
// shock-immune). Alpha stores x = u*r = a_raw/p (division-free); beta stores
// raw rows REVERSED (slot j = reference b[t][j]). Row sums stored fp32.
__global__ __launch_bounds__(64) void chain_kernel(
    const float* __restrict__ gout, const int* __restrict__ glabel,
    const int* __restrict__ gw, ushort2* __restrict__ a_st,
    ushort2* __restrict__ b_st, float* __restrict__ sums_a,
    float* __restrict__ sums_b) {
  const int bx = blockIdx.x;
  const int b = bx >> 1, ph = bx & 1;
  const int i = threadIdx.x;
  const float* P = gout + (size_t)b * (NC * MT);  // P[c*MT + t]
  const int* lab = glabel + b * UL;
  const int T = gw[b] >> 2;  // [128,256]

  const int s0 = 2 * i, s1 = s0 + 1;
  const float h0f = (i <= 40) ? 1.f : 0.f;
  const float h1f = (i <= 39) ? 1.f : 0.f;
  const int iw = (i <= 40) ? i : 40;

  const float* pB;
  const float* pL;
  float mskf;
  ushort2* rows;
  float* sums;
  if (ph == 0) {  // alpha
    const int li = (i < UL) ? lab[i] : 0;
    const int lm = (i >= 1 && i < UL) ? lab[i - 1] : 0;
    pB = P;
    pL = P + (size_t)li * MT;
    mskf = (i >= 1 && i <= 39 && li != lm) ? 1.f : 0.f;
    rows = a_st + (size_t)b * MT * PAIRS;
    sums = sums_a + (size_t)b * MT;
  } else {  // beta: class-flipped probs, reversed labels
    const int rli = (i < UL) ? lab[UL - 1 - i] : 0;
    const int rlm = (i >= 1 && i < UL) ? lab[UL - i] : 0;
    pB = P + (size_t)(NC - 1) * MT;
    pL = P + (size_t)(NC - 1 - rli) * MT;
    mskf = (i >= 1 && i <= 39 && rli != rlm) ? 1.f : 0.f;
    rows = b_st + (size_t)b * MT * PAIRS;
    sums = sums_b + (size_t)b * MT;
  }

  // t = 0
  float v0 = (i == 0) ? pB[0] : 0.f;
  float v1 = (i == 0) ? pL[0] : 0.f;
  float ss = wave_sum(v0 + v1);
  if (i == 0) sums[0] = ss;
  float r0q = FQ * fast_rcp(fmaxf(ss, SEPS));
  float r1q = FQ * fast_rcp(fmaxf(ss * r0q, SEPS));
  float r2q = FQ * fast_rcp(fmaxf(ss * r0q * r1q, SEPS));

  ushort2* wa = rows + iw;         // alpha: row t, pair i
  ushort2* wb = rows + (40 - iw);  // beta: row t-1 (delayed), rev pair
  if (ph == 0) {
    // x row 0 = a_raw/p: 1 at lane 0 (both slots), else 0
    if (i <= 40) *wa = pack2((i == 0) ? 1.f : 0.f, (i == 0) ? 1.f : 0.f);
    wa += PAIRS;
  }

  float pbq0 = pB[1], pbq1 = pB[2], pbq2 = pB[3];
  float plq0 = pL[1], plq1 = pL[2], plq2 = pL[3];
  for (int t = 1; t < T; ++t) {
    float pm1 = wave_shr1(v1);  // prev row, state 2i-1
    if (ph == 1) {              // store prev beta row reversed: (raw2i, raw2i-1)
      if (i <= 40) *wb = pack2(v0, pm1);
      wb += PAIRS;
    }
    const float rh0 = r0q * h0f, rh1 = r0q * h1f;
    float u0 = v0 + pm1;
    float u1 = (v0 + v1) + pm1 * mskf;
    const int start = LS - 2 * (T - t);
    if (s0 < start) u0 = 0.f;
    if (s1 < start) u1 = 0.f;
    const float x0 = u0 * rh0, x1 = u1 * rh1;  // = n/p exactly
    float n0 = x0 * pbq0;
    float n1 = x1 * plq0;
    if (ph == 0) {
      if (i <= 40) *wa = pack2(x0, x1);
      wa += PAIRS;
    }
    float ssn = wave_sum(n0 + n1);
    if (i == 0) sums[t] = ssn;
    float rn = FQ * fast_rcp(fmaxf(ssn, SEPS) * r1q * r2q);
    rn = fminf(fmaxf(rn, 1e-20f), 1e20f);  // close inf->NaN feedback loop
    r0q = r1q; r1q = r2q; r2q = rn;
    int tn = t + 3; if (tn > T - 1) tn = T - 1;
    pbq0 = pbq1; pbq1 = pbq2; pbq2 = pB[tn];
    plq0 = plq1; plq1 = plq2; plq2 = pL[tn];
    v0 = n0; v1 = n1;
  }
  if (ph == 1) {  // final beta row T-1
    float pm1f = wave_shr1(v1);
    if (i <= 40) *wb = pack2(v0, pm1f);
  }
}

// Fully parallel combine: block = item, wave w handles t = w, w+4, ...
// lh_t = sum_s x[t][s]*brev[T-1-t][s] / (sa_t * sb_{T-1-t}).
__global__ __launch_bounds__(256) void combine_kernel(
    const int* __restrict__ gw, const ushort2* __restrict__ a_st,
    const ushort2* __restrict__ b_st, const float* __restrict__ sums_a,
    const float* __restrict__ sums_b, float* __restrict__ loss_out) {
  const int b = blockIdx.x;
  const int w = threadIdx.x >> 6;
  const int i = threadIdx.x & 63;
  const int T = gw[b] >> 2;
  const ushort2* A = a_st + (size_t)b * MT * PAIRS;
  const ushort2* Bs = b_st + (size_t)b * MT * PAIRS;
  const float* sa = sums_a + (size_t)b * MT;
  const float* sb = sums_b + (size_t)b * MT;
  const int iw = (i <= 40) ? i : 40;
  const float hv = (i <= 40) ? 1.f : 0.f;

  float lsum = 0.f;
  for (int t = w; t < T; t += 4) {
    const ushort2 ap = A[(size_t)t * PAIRS + iw];
    const ushort2 bp = Bs[(size_t)(T - 1 - t) * PAIRS + iw];
    float d = (bf2f(ap.x) * bf2f(bp.x) + bf2f(ap.y) * bf2f(bp.y)) * hv;
    d = wave_sum(d);
    float lh = d * fast_rcp(fmaxf(sa[t], SEPS)) *
               fast_rcp(fmaxf(sb[T - 1 - t], SEPS));
    lsum -= __logf(fmaxf(lh, 1e-37f));
  }
  __shared__ float part[4];
  if (i == 0) part[w] = lsum;
  __syncthreads();
  if (threadIdx.x == 0) {
    float L = part[0] + part[1] + part[2] + part[3];
    loss_out[b] = fminf(fmaxf(L, -1e30f), 1e30f);  // fmin/fmax absorb NaN
  }
}

__global__ void reduce_kernel(const float* __restrict__ loss_in,
                              float* __restrict__ out) {
  __shared__ double sm[256];
  const int tid = threadIdx.x;
  double s = 0.0;
  for (int k = tid; k < BN; k += 256) s += (double)loss_in[k];
  sm[tid] = s;
  __syncthreads();
  for (int w = 128; w >= 1; w >>= 1) {
    if (tid < w) sm[tid] += sm[tid + w];
    __syncthreads();
  }
  if (tid == 0) out[0] = (float)sm[0];
}
}  // namespace

extern "C" void kernel_launch(void* const* d_in, const int* in_sizes, int n_in,
                              void* d_out, int out_size, void* d_ws, size_t ws_size,
                              hipStream_t stream) {
  const float* gout = (const float*)d_in[0];
  const int* glabel = (const int*)d_in[1];
  const int* gw = (const int*)d_in[2];
  ushort2* a_st = (ushort2*)d_ws;                    // 1024*256*41 pairs (43 MB)
  ushort2* b_st = a_st + (size_t)BN * MT * PAIRS;    // 43 MB
  float* sums_a = (float*)(b_st + (size_t)BN * MT * PAIRS);  // 1 MB
  float* sums_b = sums_a + (size_t)BN * MT;                  // 1 MB
  float* loss = sums_b + (size_t)BN * MT;                    // 4 KB
  chain_kernel<<<2 * BN, 64, 0, stream>>>(gout, glabel, gw, a_st, b_st,
                                          sums_a, sums_b);
  combine_kernel<<<BN, 256, 0, stream>>>(gw, a_st, b_st, sums_a, sums_b, loss);
  reduce_kernel<<<1, 256, 0, stream>>>(loss, (float*)d_out);
}